// Round 1
// baseline (140.640 us; speedup 1.0000x reference)
//
#include <hip/hip_runtime.h>
#include <hip/hip_bf16.h>

// FSMN memory block: strided dilated depthwise conv over time + residual.
// inputs: (B=16, T=2000, D=512) f32; filt: (16, 512) f32.
// out[b,t,d] = sum_{k=0..9}  x[b, t-(10-k)*2, d] * filt[k,d]        (left taps)
//            + x[b,t,d] * filt[10,d]                                  (center)
//            + sum_{k=0..4} x[b, t+1+k*2,   d] * filt[11+k,d]        (right taps)
//            + x[b,t,d]                                               (residual)
// Out-of-range time indices contribute zero.

constexpr int B = 16;
constexpr int T = 2000;
constexpr int D = 512;
constexpr int D4 = D / 4;          // 128 float4 per (b,t) row
constexpr int L_ORDER = 10;
constexpr int R_ORDER = 5;
constexpr int L_STRIDE = 2;
constexpr int R_STRIDE = 2;

__global__ __launch_bounds__(256) void fsmn_kernel(
    const float4* __restrict__ x,      // (B*T*D4)
    const float4* __restrict__ filt,   // (16*D4)
    float4* __restrict__ out)          // (B*T*D4)
{
    const int idx = blockIdx.x * blockDim.x + threadIdx.x;
    // total = B*T*D4 = 4,096,000; grid sized exactly (16000 * 256), no bounds check needed
    const int d4 = idx & (D4 - 1);       // D4 = 128, power of two
    const int bt = idx >> 7;             // idx / D4
    const int t  = bt % T;
    const int b  = bt / T;
    const int rowbase = b * T;           // in units of rows

    // center tap + residual folded: x * (filt[10] + 1)
    float4 xin = x[idx];
    float4 fc  = filt[L_ORDER * D4 + d4];
    float4 acc;
    acc.x = xin.x * (fc.x + 1.0f);
    acc.y = xin.y * (fc.y + 1.0f);
    acc.z = xin.z * (fc.z + 1.0f);
    acc.w = xin.w * (fc.w + 1.0f);

    // left taps: k=0..9, time offset -(10-k)*2  (i.e. -20..-2)
#pragma unroll
    for (int k = 0; k < L_ORDER; ++k) {
        const int tt = t - (L_ORDER - k) * L_STRIDE;
        if (tt >= 0) {
            float4 xv = x[(rowbase + tt) * D4 + d4];
            float4 fv = filt[k * D4 + d4];
            acc.x = fmaf(xv.x, fv.x, acc.x);
            acc.y = fmaf(xv.y, fv.y, acc.y);
            acc.z = fmaf(xv.z, fv.z, acc.z);
            acc.w = fmaf(xv.w, fv.w, acc.w);
        }
    }

    // right taps: k=0..4, time offset +1+k*2  (i.e. +1,+3,+5,+7,+9)
#pragma unroll
    for (int k = 0; k < R_ORDER; ++k) {
        const int tt = t + 1 + k * R_STRIDE;
        if (tt < T) {
            float4 xv = x[(rowbase + tt) * D4 + d4];
            float4 fv = filt[(L_ORDER + 1 + k) * D4 + d4];
            acc.x = fmaf(xv.x, fv.x, acc.x);
            acc.y = fmaf(xv.y, fv.y, acc.y);
            acc.z = fmaf(xv.z, fv.z, acc.z);
            acc.w = fmaf(xv.w, fv.w, acc.w);
        }
    }

    out[idx] = acc;
}

extern "C" void kernel_launch(void* const* d_in, const int* in_sizes, int n_in,
                              void* d_out, int out_size, void* d_ws, size_t ws_size,
                              hipStream_t stream) {
    const float4* x    = (const float4*)d_in[0];
    const float4* filt = (const float4*)d_in[1];
    float4* out        = (float4*)d_out;

    const int total = B * T * D4;                 // 4,096,000
    const int block = 256;
    const int grid  = total / block;              // 16000, exact
    fsmn_kernel<<<grid, block, 0, stream>>>(x, filt, out);
}

// Round 2
// 72.311 us; speedup vs baseline: 1.9449x; 1.9449x over previous
//
#include <hip/hip_runtime.h>
#include <hip/hip_bf16.h>

// FSMN memory block: strided dilated depthwise conv over time + residual.
// inputs: (B=16, T=2000, D=512) f32; filt: (16, 512) f32.
// out[b,t,d] = sum_{k=0..9}  x[b, t-(10-k)*2, d] * filt[k,d]        (left taps)
//            + x[b,t,d] * filt[10,d]                                  (center)
//            + sum_{k=0..4} x[b, t+1+k*2,   d] * filt[11+k,d]        (right taps)
//            + x[b,t,d]                                               (residual)
// Out-of-range time indices contribute zero.
//
// R1 finding: default round-robin blockIdx->XCD mapping caused 7.2x L2
// over-fetch (FETCH_SIZE 470 MB vs 65.5 MB ideal). Fix: chunked XCD swizzle
// so each XCD's L2 sees a contiguous bt range.

constexpr int B = 16;
constexpr int T = 2000;
constexpr int D = 512;
constexpr int D4 = D / 4;          // 128 float4 per (b,t) row
constexpr int L_ORDER = 10;
constexpr int R_ORDER = 5;
constexpr int L_STRIDE = 2;
constexpr int R_STRIDE = 2;
constexpr int NXCD = 8;

__global__ __launch_bounds__(256) void fsmn_kernel(
    const float4* __restrict__ x,      // (B*T*D4)
    const float4* __restrict__ filt,   // (16*D4)
    float4* __restrict__ out)          // (B*T*D4)
{
    // XCD-aware chunked swizzle: hardware round-robins blockIdx across the
    // 8 XCDs; remap so XCD j processes the contiguous chunk j of the grid.
    // gridDim.x = 16000 (divisible by 8) -> bijective.
    const int cpx   = gridDim.x >> 3;            // chunks per XCD
    const int wg    = (blockIdx.x & (NXCD - 1)) * cpx + (blockIdx.x >> 3);
    const int idx   = wg * blockDim.x + threadIdx.x;

    const int d4 = idx & (D4 - 1);       // D4 = 128, power of two
    const int bt = idx >> 7;             // idx / D4
    const int t  = bt % T;
    const int b  = bt / T;
    const int rowbase = b * T;           // in units of rows

    // center tap + residual folded: x * (filt[10] + 1)
    float4 xin = x[idx];
    float4 fc  = filt[L_ORDER * D4 + d4];
    float4 acc;
    acc.x = xin.x * (fc.x + 1.0f);
    acc.y = xin.y * (fc.y + 1.0f);
    acc.z = xin.z * (fc.z + 1.0f);
    acc.w = xin.w * (fc.w + 1.0f);

    // left taps: k=0..9, time offset -(10-k)*2  (i.e. -20..-2)
#pragma unroll
    for (int k = 0; k < L_ORDER; ++k) {
        const int tt = t - (L_ORDER - k) * L_STRIDE;
        if (tt >= 0) {
            float4 xv = x[(rowbase + tt) * D4 + d4];
            float4 fv = filt[k * D4 + d4];
            acc.x = fmaf(xv.x, fv.x, acc.x);
            acc.y = fmaf(xv.y, fv.y, acc.y);
            acc.z = fmaf(xv.z, fv.z, acc.z);
            acc.w = fmaf(xv.w, fv.w, acc.w);
        }
    }

    // right taps: k=0..4, time offset +1+k*2  (i.e. +1,+3,+5,+7,+9)
#pragma unroll
    for (int k = 0; k < R_ORDER; ++k) {
        const int tt = t + 1 + k * R_STRIDE;
        if (tt < T) {
            float4 xv = x[(rowbase + tt) * D4 + d4];
            float4 fv = filt[(L_ORDER + 1 + k) * D4 + d4];
            acc.x = fmaf(xv.x, fv.x, acc.x);
            acc.y = fmaf(xv.y, fv.y, acc.y);
            acc.z = fmaf(xv.z, fv.z, acc.z);
            acc.w = fmaf(xv.w, fv.w, acc.w);
        }
    }

    out[idx] = acc;
}

extern "C" void kernel_launch(void* const* d_in, const int* in_sizes, int n_in,
                              void* d_out, int out_size, void* d_ws, size_t ws_size,
                              hipStream_t stream) {
    const float4* x    = (const float4*)d_in[0];
    const float4* filt = (const float4*)d_in[1];
    float4* out        = (float4*)d_out;

    const int total = B * T * D4;                 // 4,096,000
    const int block = 256;
    const int grid  = total / block;              // 16000, exact, divisible by 8
    fsmn_kernel<<<grid, block, 0, stream>>>(x, filt, out);
}

// Round 3
// 29.994 us; speedup vs baseline: 4.6889x; 2.4108x over previous
//
#include <hip/hip_runtime.h>
#include <hip/hip_bf16.h>

// FSMN: strided dilated depthwise conv over time + residual.
// R2 finding: 16 tap-loads/thread => ~1.05 GB through L1/L2 pipes; only
// 1.2 TB/s HBM => cache-pipe-bound, not HBM-bound.
// R3 fix: register sliding window. Thread owns one d column, S=50 consecutive
// t outputs. Circular W[32] covers [t-20, t+11]; per 2 outputs: 2 loads,
// 32 FMA, 2 stores. Each element loaded ~1.6x (strip halo) vs 16x before.

constexpr int B = 16;
constexpr int T = 2000;
constexpr int D = 512;
constexpr int NTAP = 16;          // rows of filt: 0..9 left, 10 center, 11..15 right
constexpr int S = 50;             // outputs per thread strip
constexpr int NSTRIP = T / S;     // 40
constexpr int ITERS = S / 2;      // 25 double-steps
constexpr int NXCD = 8;

__global__ __launch_bounds__(256) void fsmn_sw_kernel(
    const float* __restrict__ x,      // (B,T,D)
    const float* __restrict__ filt,   // (16,D)
    float* __restrict__ out)          // (B,T,D)
{
    // grid = B*2*NSTRIP = 1280 blocks; bid -> (b, dhalf, strip), strip fastest
    // so adjacent strips (sharing halo rows) land on the same XCD chunk.
    const int nbl = B * 2 * NSTRIP;          // 1280
    const int cpx = nbl / NXCD;              // 160
    int bid = blockIdx.x;
    bid = (bid & (NXCD - 1)) * cpx + (bid >> 3);   // chunked XCD swizzle

    const int strip = bid % NSTRIP;
    const int bd    = bid / NSTRIP;          // 0..31
    const int dhalf = bd & 1;
    const int b     = bd >> 1;
    const int d     = dhalf * 256 + (int)threadIdx.x;
    const int t0    = strip * S;

    const float* xp = x + (size_t)(b * T) * D + d;        // xp[p*D] = x[b,p,d]
    float*       op = out + (size_t)(b * T + t0) * D + d; // op[i*D] = out[b,t0+i,d]

    // filter taps for this d, residual folded into center tap
    float F[NTAP];
#pragma unroll
    for (int k = 0; k < NTAP; ++k) F[k] = filt[k * D + d];
    F[10] += 1.0f;

    // circular window: W[(p - (t0-20)) & 31] holds x[b, p, d]
    float W[32];
#pragma unroll
    for (int m = 0; m < 32; ++m) {
        const int p = t0 - 20 + m;            // p <= t0+11 <= 1961 < T always
        W[m] = (p >= 0) ? xp[p * D] : 0.0f;
    }

#pragma unroll
    for (int i = 0; i < ITERS; ++i) {
        const int j = (2 * i) & 31;           // compile-time after unroll
        // tap k=0 (positions t-20, t-19) consumed FIRST so slots j, j+1
        // can be immediately reused by the prefetch loads below.
        float a0 = W[j] * F[0];
        float a1 = W[(j + 1) & 31] * F[0];

        // prefetch the next double-step's two new positions (t+12, t+13)
        if (i + 1 < ITERS) {
            const int p0 = t0 + 2 * i + 12;
            const int p1 = p0 + 1;
            W[j]            = (p0 < T) ? xp[p0 * D] : 0.0f;
            W[(j + 1) & 31] = (p1 < T) ? xp[p1 * D] : 0.0f;
        }

        // even-offset taps k=1..10 (rel = 2k-20); center k=10 has +1 folded
#pragma unroll
        for (int k = 1; k <= 10; ++k) {
            a0 = fmaf(W[(j + 2 * k) & 31],     F[k], a0);
            a1 = fmaf(W[(j + 1 + 2 * k) & 31], F[k], a1);
        }
        // odd-offset taps k=11..15 (rel = 2k-21)
#pragma unroll
        for (int k = 11; k <= 15; ++k) {
            a0 = fmaf(W[(j + 2 * k - 1) & 31], F[k], a0);
            a1 = fmaf(W[(j + 2 * k) & 31],     F[k], a1);
        }

        op[(2 * i) * D]     = a0;
        op[(2 * i + 1) * D] = a1;
    }
}

extern "C" void kernel_launch(void* const* d_in, const int* in_sizes, int n_in,
                              void* d_out, int out_size, void* d_ws, size_t ws_size,
                              hipStream_t stream) {
    const float* x    = (const float*)d_in[0];
    const float* filt = (const float*)d_in[1];
    float* out        = (float*)d_out;

    const int grid = B * 2 * NSTRIP;   // 1280 blocks, exactly 5 per CU, /8 XCDs
    fsmn_sw_kernel<<<grid, 256, 0, stream>>>(x, filt, out);
}

// Round 4
// 28.843 us; speedup vs baseline: 4.8760x; 1.0399x over previous
//
#include <hip/hip_runtime.h>
#include <hip/hip_bf16.h>

// FSMN: strided dilated depthwise conv over time + residual.
// R3 finding: latency-bound (VALUBusy 19%, HBM 48%, occ 21%) — prefetch depth
// of 1 double-step gives only ~64 cycles of vmcnt slack vs ~500-900 cycle miss
// latency. R4 fix: prefetch P=4 double-steps ahead (ring 38), nontemporal
// stores to keep L2/L3 for the input halo reuse.

constexpr int B = 16;
constexpr int T = 2000;
constexpr int D = 512;
constexpr int NTAP = 16;          // filt rows: 0..9 left, 10 center, 11..15 right
constexpr int S = 50;             // outputs per thread strip
constexpr int NSTRIP = T / S;     // 40
constexpr int ITERS = S / 2;      // 25 double-steps
constexpr int NXCD = 8;
constexpr int P = 4;              // prefetch depth in double-steps
constexpr int RING = 32 + 2 * (P - 1);   // 38 live positions: [t-20, t+17]

__global__ __launch_bounds__(256) void fsmn_sw_kernel(
    const float* __restrict__ x,      // (B,T,D)
    const float* __restrict__ filt,   // (16,D)
    float* __restrict__ out)          // (B,T,D)
{
    // grid = B*2*NSTRIP = 1280 blocks; bid -> (b, dhalf, strip), strip fastest
    // so adjacent strips (sharing halo rows) land on the same XCD chunk.
    const int nbl = B * 2 * NSTRIP;          // 1280
    const int cpx = nbl / NXCD;              // 160
    int bid = blockIdx.x;
    bid = (bid & (NXCD - 1)) * cpx + (bid >> 3);   // chunked XCD swizzle

    const int strip = bid % NSTRIP;
    const int bd    = bid / NSTRIP;          // 0..31
    const int dhalf = bd & 1;
    const int b     = bd >> 1;
    const int d     = dhalf * 256 + (int)threadIdx.x;
    const int t0    = strip * S;

    const float* xp = x + (size_t)(b * T) * D + d;        // xp[p*D] = x[b,p,d]
    float*       op = out + (size_t)(b * T + t0) * D + d; // op[i*D] = out[b,t0+i,d]

    // filter taps for this d, residual folded into center tap
    float F[NTAP];
#pragma unroll
    for (int k = 0; k < NTAP; ++k) F[k] = filt[k * D + d];
    F[10] += 1.0f;

    // ring window: W[(p - (t0-20)) % RING] holds x[b, p, d]
    // initial fill covers [t0-20, t0+17] (prefetched through iter P-1)
    float W[RING];
#pragma unroll
    for (int m = 0; m < RING; ++m) {
        const int p = t0 - 20 + m;
        W[m] = (p >= 0 && p < T) ? xp[p * D] : 0.0f;
    }

#pragma unroll
    for (int i = 0; i < ITERS; ++i) {
        const int base = (2 * i) % RING;      // slot of (t-20), t = t0+2i
        // tap k=0 consumed FIRST: slots base, base+1 are reused by the
        // prefetch writes below (they hold the oldest positions).
        float a0 = W[base] * F[0];
        float a1 = W[(base + 1) % RING] * F[0];

        // prefetch the pair first consumed at iteration i+P
        if (i + P < ITERS) {
            const int p0 = t0 + 18 + 2 * i;   // next two above window top
            const int p1 = p0 + 1;
            W[base]              = (p0 < T) ? xp[p0 * D] : 0.0f;
            W[(base + 1) % RING] = (p1 < T) ? xp[p1 * D] : 0.0f;
        }

        // even-offset taps k=1..10 (rel = 2k-20); center k=10 has +1 folded
#pragma unroll
        for (int k = 1; k <= 10; ++k) {
            a0 = fmaf(W[(base + 2 * k) % RING],     F[k], a0);
            a1 = fmaf(W[(base + 1 + 2 * k) % RING], F[k], a1);
        }
        // odd-offset taps k=11..15 (rel = 2k-21)
#pragma unroll
        for (int k = 11; k <= 15; ++k) {
            a0 = fmaf(W[(base + 2 * k - 1) % RING], F[k], a0);
            a1 = fmaf(W[(base + 2 * k) % RING],     F[k], a1);
        }

        // nontemporal: output is never re-read — don't evict input from L2/L3
        __builtin_nontemporal_store(a0, &op[(2 * i) * D]);
        __builtin_nontemporal_store(a1, &op[(2 * i + 1) * D]);
    }
}

extern "C" void kernel_launch(void* const* d_in, const int* in_sizes, int n_in,
                              void* d_out, int out_size, void* d_ws, size_t ws_size,
                              hipStream_t stream) {
    const float* x    = (const float*)d_in[0];
    const float* filt = (const float*)d_in[1];
    float* out        = (float*)d_out;

    const int grid = B * 2 * NSTRIP;   // 1280 blocks = 5 per CU exactly, /8 XCDs
    fsmn_sw_kernel<<<grid, 256, 0, stream>>>(x, filt, out);
}

// Round 5
// 25.493 us; speedup vs baseline: 5.5168x; 1.1314x over previous
//
#include <hip/hip_runtime.h>
#include <hip/hip_bf16.h>

// FSMN: strided dilated depthwise conv over time + residual.
// R4 finding: deeper per-wave prefetch ~neutral. Occupancy 21%: grid of 1280
// blocks (5/CU) is fully co-resident -> TLP-starved, not MLP-starved.
// R5 fix: shorter strips S=20 -> 3200 blocks (12.5/CU, full 32-wave residency
// + backfill). Halo loads/output rise to 2.5x but stay L2-resident (XCD-chunked
// swizzle keeps neighbor strips on the same XCD), so HBM traffic ~flat.

constexpr int B = 16;
constexpr int T = 2000;
constexpr int D = 512;
constexpr int NTAP = 16;          // filt rows: 0..9 left, 10 center, 11..15 right
constexpr int S = 20;             // outputs per thread strip
constexpr int NSTRIP = T / S;     // 100
constexpr int ITERS = S / 2;      // 10 double-steps
constexpr int NXCD = 8;
constexpr int P = 4;              // prefetch depth in double-steps
constexpr int RING = 32 + 2 * (P - 1);   // 38 live positions: [t-20, t+17]

__global__ __launch_bounds__(256) void fsmn_sw_kernel(
    const float* __restrict__ x,      // (B,T,D)
    const float* __restrict__ filt,   // (16,D)
    float* __restrict__ out)          // (B,T,D)
{
    // grid = B*2*NSTRIP = 3200 blocks; bid -> (b, dhalf, strip), strip fastest
    // so adjacent strips (sharing halo rows) land on the same XCD chunk.
    const int nbl = B * 2 * NSTRIP;          // 3200
    const int cpx = nbl / NXCD;              // 400
    int bid = blockIdx.x;
    bid = (bid & (NXCD - 1)) * cpx + (bid >> 3);   // chunked XCD swizzle

    const int strip = bid % NSTRIP;
    const int bd    = bid / NSTRIP;          // 0..31
    const int dhalf = bd & 1;
    const int b     = bd >> 1;
    const int d     = dhalf * 256 + (int)threadIdx.x;
    const int t0    = strip * S;

    const float* xp = x + (size_t)(b * T) * D + d;        // xp[p*D] = x[b,p,d]
    float*       op = out + (size_t)(b * T + t0) * D + d; // op[i*D] = out[b,t0+i,d]

    // filter taps for this d, residual folded into center tap
    float F[NTAP];
#pragma unroll
    for (int k = 0; k < NTAP; ++k) F[k] = filt[k * D + d];
    F[10] += 1.0f;

    // ring window: W[(p - (t0-20)) % RING] holds x[b, p, d]
    // initial fill covers [t0-20, t0+17]; p <= t0+17 <= 1997 < T always.
    float W[RING];
#pragma unroll
    for (int m = 0; m < RING; ++m) {
        const int p = t0 - 20 + m;
        W[m] = (p >= 0) ? xp[p * D] : 0.0f;
    }

#pragma unroll
    for (int i = 0; i < ITERS; ++i) {
        const int base = (2 * i) % RING;      // slot of (t-20), t = t0+2i
        // tap k=0 consumed FIRST: slots base, base+1 hold the oldest rows and
        // are immediately reused by the prefetch writes below.
        float a0 = W[base] * F[0];
        float a1 = W[(base + 1) % RING] * F[0];

        // prefetch the pair first consumed ~P iterations ahead
        if (i + P < ITERS) {
            const int p0 = t0 + 18 + 2 * i;
            const int p1 = p0 + 1;
            W[base]              = (p0 < T) ? xp[p0 * D] : 0.0f;
            W[(base + 1) % RING] = (p1 < T) ? xp[p1 * D] : 0.0f;
        }

        // even-offset taps k=1..10 (rel = 2k-20); center k=10 has +1 folded
#pragma unroll
        for (int k = 1; k <= 10; ++k) {
            a0 = fmaf(W[(base + 2 * k) % RING],     F[k], a0);
            a1 = fmaf(W[(base + 1 + 2 * k) % RING], F[k], a1);
        }
        // odd-offset taps k=11..15 (rel = 2k-21)
#pragma unroll
        for (int k = 11; k <= 15; ++k) {
            a0 = fmaf(W[(base + 2 * k - 1) % RING], F[k], a0);
            a1 = fmaf(W[(base + 2 * k) % RING],     F[k], a1);
        }

        // nontemporal: output is never re-read — don't evict input from L2/L3
        __builtin_nontemporal_store(a0, &op[(2 * i) * D]);
        __builtin_nontemporal_store(a1, &op[(2 * i + 1) * D]);
    }
}

extern "C" void kernel_launch(void* const* d_in, const int* in_sizes, int n_in,
                              void* d_out, int out_size, void* d_ws, size_t ws_size,
                              hipStream_t stream) {
    const float* x    = (const float*)d_in[0];
    const float* filt = (const float*)d_in[1];
    float* out        = (float*)d_out;

    const int grid = B * 2 * NSTRIP;   // 3200 blocks, /8 XCDs evenly
    fsmn_sw_kernel<<<grid, 256, 0, stream>>>(x, filt, out);
}